// Round 1
// baseline (1143.030 us; speedup 1.0000x reference)
//
#include <hip/hip_runtime.h>
#include <hip/hip_bf16.h>

#define LRELU_ALPHA 0.3f
#define LN_EPS 1e-3f

// ---------------------------------------------------------------------------
// Generic tiled fp32 GEMM: C[M,N] = A[M,K](lda) @ W[K,N] + bias[N]
// 16x16 tiles, one output per thread. Correctness-first; MFMA comes later.
// ---------------------------------------------------------------------------
__global__ void gemm_bias(const float* __restrict__ A, int lda,
                          const float* __restrict__ W,
                          const float* __restrict__ bias,
                          float* __restrict__ C,
                          int M, int N, int K) {
    __shared__ float As[16][17];
    __shared__ float Ws[16][17];
    const int tx = threadIdx.x, ty = threadIdx.y;
    const int row = blockIdx.y * 16 + ty;
    const int col = blockIdx.x * 16 + tx;
    float acc = 0.f;
    for (int k0 = 0; k0 < K; k0 += 16) {
        const int ka = k0 + tx;
        As[ty][tx] = (row < M && ka < K) ? A[(size_t)row * lda + ka] : 0.f;
        const int kw = k0 + ty;
        Ws[ty][tx] = (kw < K && col < N) ? W[(size_t)kw * N + col] : 0.f;
        __syncthreads();
#pragma unroll
        for (int kk = 0; kk < 16; ++kk) acc += As[ty][kk] * Ws[kk][tx];
        __syncthreads();
    }
    if (row < M && col < N) C[(size_t)row * N + col] = acc + bias[col];
}

// ---------------------------------------------------------------------------
// Batch diversity: t (N,15) -> dv (N,5)
// dv[i,k] = sum_j exp(-sum_{d<3} |t[i,3k+d]-t[j,3k+d]|)   (includes j==i)
// One block (256 thr) per row i; threads stride over j; shuffle-reduce.
// ---------------------------------------------------------------------------
__global__ void diversity_kernel(const float* __restrict__ t,
                                 float* __restrict__ dv, int N) {
    const int i = blockIdx.x;
    const int tid = threadIdx.x;
    float ti[15];
#pragma unroll
    for (int d = 0; d < 15; ++d) ti[d] = t[i * 15 + d];
    float acc[5] = {0.f, 0.f, 0.f, 0.f, 0.f};
    for (int j = tid; j < N; j += 256) {
        const float* tj = t + j * 15;
#pragma unroll
        for (int k = 0; k < 5; ++k) {
            float s = fabsf(ti[3 * k]     - tj[3 * k])
                    + fabsf(ti[3 * k + 1] - tj[3 * k + 1])
                    + fabsf(ti[3 * k + 2] - tj[3 * k + 2]);
            acc[k] += __expf(-s);
        }
    }
    __shared__ float red[5][4];
    const int lane = tid & 63, wave = tid >> 6;
#pragma unroll
    for (int k = 0; k < 5; ++k) {
        float v = acc[k];
#pragma unroll
        for (int off = 32; off > 0; off >>= 1) v += __shfl_down(v, off, 64);
        if (lane == 0) red[k][wave] = v;
    }
    __syncthreads();
    if (tid < 5) {
        dv[i * 5 + tid] = red[tid][0] + red[tid][1] + red[tid][2] + red[tid][3];
    }
}

// ---------------------------------------------------------------------------
// Fused concat([h, dv]) -> LayerNorm(center-only) -> LeakyReLU
// One block (256 thr) per row. C = H + D = 1029, so <= 5 elems/thread.
// ---------------------------------------------------------------------------
__global__ void ln_lrelu(const float* __restrict__ h, const float* __restrict__ dvf,
                         const float* __restrict__ beta, float* __restrict__ out,
                         int H, int D) {
    const int i = blockIdx.x;
    const int tid = threadIdx.x;
    const int C = H + D;
    float v[5];
    float s = 0.f, s2 = 0.f;
#pragma unroll
    for (int r = 0; r < 5; ++r) {
        const int c = tid + r * 256;
        if (c < C) {
            const float x = (c < H) ? h[(size_t)i * H + c] : dvf[i * D + (c - H)];
            v[r] = x;
            s += x;
            s2 += x * x;
        }
    }
    __shared__ float rs[4], rs2[4];
    const int lane = tid & 63, wave = tid >> 6;
#pragma unroll
    for (int off = 32; off > 0; off >>= 1) {
        s  += __shfl_down(s, off, 64);
        s2 += __shfl_down(s2, off, 64);
    }
    if (lane == 0) { rs[wave] = s; rs2[wave] = s2; }
    __syncthreads();
    const float S  = rs[0] + rs[1] + rs[2] + rs[3];
    const float S2 = rs2[0] + rs2[1] + rs2[2] + rs2[3];
    const float mu = S / (float)C;
    const float var = S2 / (float)C - mu * mu;
    const float rstd = rsqrtf(var + LN_EPS);
#pragma unroll
    for (int r = 0; r < 5; ++r) {
        const int c = tid + r * 256;
        if (c < C) {
            float y = (v[r] - mu) * rstd + beta[c];
            out[(size_t)i * C + c] = (y >= 0.f) ? y : LRELU_ALPHA * y;
        }
    }
}

// ---------------------------------------------------------------------------
// Critic head: out[i] = hc[i,:] . wf + bf   (C = 1029)
// ---------------------------------------------------------------------------
__global__ void head_kernel(const float* __restrict__ hc, const float* __restrict__ wf,
                            const float* __restrict__ bf, float* __restrict__ out,
                            int C) {
    const int i = blockIdx.x;
    const int tid = threadIdx.x;
    float s = 0.f;
    for (int c = tid; c < C; c += 256) s += hc[(size_t)i * C + c] * wf[c];
    __shared__ float rs[4];
    const int lane = tid & 63, wave = tid >> 6;
#pragma unroll
    for (int off = 32; off > 0; off >>= 1) s += __shfl_down(s, off, 64);
    if (lane == 0) rs[wave] = s;
    __syncthreads();
    if (tid == 0) out[i] = rs[0] + rs[1] + rs[2] + rs[3] + bf[0];
}

extern "C" void kernel_launch(void* const* d_in, const int* in_sizes, int n_in,
                              void* d_out, int out_size, void* d_ws, size_t ws_size,
                              hipStream_t stream) {
    const float* x     = (const float*)d_in[0];   // (4096, 512)
    const float* w0a   = (const float*)d_in[1];   // (512, 1024)
    const float* b0a   = (const float*)d_in[2];   // (1024,)
    const float* w0b   = (const float*)d_in[3];   // (1024, 15)
    const float* b0b   = (const float*)d_in[4];   // (15,)
    const float* beta0 = (const float*)d_in[5];   // (1029,)
    const float* w1a   = (const float*)d_in[6];   // (1029, 1024)
    const float* b1a   = (const float*)d_in[7];   // (1024,)
    const float* w1b   = (const float*)d_in[8];   // (1024, 15)
    const float* b1b   = (const float*)d_in[9];   // (15,)
    const float* beta1 = (const float*)d_in[10];  // (1029,)
    const float* wf    = (const float*)d_in[11];  // (1029, 1)
    const float* bf    = (const float*)d_in[12];  // (1,)
    float* out = (float*)d_out;                   // (4096, 1) -> 4096 floats

    const int M = 4096, NF = 512, HID = 1024, KD = 15, K5 = 5, C = 1029;

    // Workspace layout (fp32), total ~34 MB; fully rewritten every call.
    float* h  = (float*)d_ws;              // (4096, 1024)
    float* hc = h  + (size_t)M * HID;      // (4096, 1029)
    float* t  = hc + (size_t)M * C;        // (4096, 15)
    float* dv = t  + (size_t)M * KD;       // (4096, 5)

    dim3 b16(16, 16);

    // ---- layer 0 ----
    gemm_bias<<<dim3(HID / 16, M / 16), b16, 0, stream>>>(x, NF, w0a, b0a, h, M, HID, NF);
    gemm_bias<<<dim3(1, M / 16), b16, 0, stream>>>(h, HID, w0b, b0b, t, M, KD, HID);
    diversity_kernel<<<M, 256, 0, stream>>>(t, dv, M);
    ln_lrelu<<<M, 256, 0, stream>>>(h, dv, beta0, hc, HID, K5);

    // ---- layer 1 ----
    gemm_bias<<<dim3(HID / 16, M / 16), b16, 0, stream>>>(hc, C, w1a, b1a, h, M, HID, C);
    gemm_bias<<<dim3(1, M / 16), b16, 0, stream>>>(h, HID, w1b, b1b, t, M, KD, HID);
    diversity_kernel<<<M, 256, 0, stream>>>(t, dv, M);
    ln_lrelu<<<M, 256, 0, stream>>>(h, dv, beta1, hc, HID, K5);

    // ---- head ----
    head_kernel<<<M, 256, 0, stream>>>(hc, wf, bf, out, C);
}

// Round 2
// 326.892 us; speedup vs baseline: 3.4967x; 3.4967x over previous
//
#include <hip/hip_runtime.h>
#include <hip/hip_bf16.h>

#define LRELU_ALPHA 0.3f
#define LN_EPS 1e-3f

typedef short bf16x8 __attribute__((ext_vector_type(8)));
typedef float f32x4 __attribute__((ext_vector_type(4)));

static __device__ __forceinline__ unsigned short f2bf(float f) {
    union { float f; unsigned u; } v; v.f = f;
    unsigned r = v.u + 0x7fffu + ((v.u >> 16) & 1u);  // RNE
    return (unsigned short)(r >> 16);
}

// ---------------------------------------------------------------------------
// Elementwise fp32 -> bf16 cast (n multiple of 4)
// ---------------------------------------------------------------------------
__global__ void cast_bf16(const float* __restrict__ X, unsigned short* __restrict__ Y, int n) {
    const int i = (blockIdx.x * 256 + threadIdx.x) * 4;
    if (i < n) {
        const float4 v = *(const float4*)(X + i);
        ushort4 o;
        o.x = f2bf(v.x); o.y = f2bf(v.y); o.z = f2bf(v.z); o.w = f2bf(v.w);
        *(ushort4*)(Y + i) = o;
    }
}

// ---------------------------------------------------------------------------
// W (K x N fp32, row-major) -> WT (N x Kp bf16, row-major), zero-pad k in [K,Kp)
// block (32,8), grid (N/32, Kp/32)
// ---------------------------------------------------------------------------
__global__ void transpose_cast(const float* __restrict__ W, unsigned short* __restrict__ WT,
                               int K, int N, int Kp) {
    __shared__ float tile[32][33];
    const int tx = threadIdx.x, ty = threadIdx.y;
    const int kb = blockIdx.y * 32, nb = blockIdx.x * 32;
#pragma unroll
    for (int i = 0; i < 32; i += 8) {
        const int k = kb + ty + i;
        tile[ty + i][tx] = (k < K) ? W[(size_t)k * N + nb + tx] : 0.f;
    }
    __syncthreads();
#pragma unroll
    for (int i = 0; i < 32; i += 8) {
        const int n = nb + ty + i;
        const int k = kb + tx;
        WT[(size_t)n * Kp + k] = f2bf(tile[tx][ty + i]);
    }
}

// ---------------------------------------------------------------------------
// bf16 MFMA GEMM: C[M,N] fp32 = A[M,Kp]bf16 @ (BT[N,Kp]bf16)^T + bias
// Block tile 128x64, BK=32, 256 threads = 4 waves, wave tile 64x32 (4x2 mfma).
// LDS rows padded 32->40 bf16 (80B) so ds_read_b128 is at most 2-way aliased.
// ---------------------------------------------------------------------------
#define LDS_STRIDE 40
__global__ __launch_bounds__(256, 4)
void mfma_gemm(const unsigned short* __restrict__ A, int lda,
               const unsigned short* __restrict__ BT, int ldb,
               const float* __restrict__ bias, float* __restrict__ C,
               int M, int N, int K) {
    __shared__ unsigned short As[128 * LDS_STRIDE];
    __shared__ unsigned short Bs[64 * LDS_STRIDE];
    const int tid = threadIdx.x;
    const int w = tid >> 6, lane = tid & 63;
    const int q = lane >> 4, m16 = lane & 15;
    const int wr = (w >> 1) * 64, wc = (w & 1) * 32;
    const int br = blockIdx.y * 128, bc = blockIdx.x * 64;

    // staging coords: each thread moves 8 bf16 (16B) per round
    const int sr = (tid * 8) >> 5;   // 0..63
    const int sc = (tid * 8) & 31;   // 0,8,16,24

    f32x4 acc[4][2] = {};

    for (int k0 = 0; k0 < K; k0 += 32) {
        const uint4 va0 = *(const uint4*)(A + (size_t)(br + sr) * lda + k0 + sc);
        const uint4 va1 = *(const uint4*)(A + (size_t)(br + sr + 64) * lda + k0 + sc);
        const uint4 vb0 = *(const uint4*)(BT + (size_t)(bc + sr) * ldb + k0 + sc);
        *(uint4*)(As + sr * LDS_STRIDE + sc) = va0;
        *(uint4*)(As + (sr + 64) * LDS_STRIDE + sc) = va1;
        *(uint4*)(Bs + sr * LDS_STRIDE + sc) = vb0;
        __syncthreads();

        bf16x8 af[4], bfr[2];
#pragma unroll
        for (int i = 0; i < 4; ++i)
            af[i] = *(const bf16x8*)(As + (wr + 16 * i + m16) * LDS_STRIDE + q * 8);
#pragma unroll
        for (int j = 0; j < 2; ++j)
            bfr[j] = *(const bf16x8*)(Bs + (wc + 16 * j + m16) * LDS_STRIDE + q * 8);
#pragma unroll
        for (int i = 0; i < 4; ++i)
#pragma unroll
            for (int j = 0; j < 2; ++j)
                acc[i][j] = __builtin_amdgcn_mfma_f32_16x16x32_bf16(af[i], bfr[j], acc[i][j], 0, 0, 0);
        __syncthreads();
    }

#pragma unroll
    for (int i = 0; i < 4; ++i) {
        const int gr = br + wr + 16 * i + q * 4;
#pragma unroll
        for (int j = 0; j < 2; ++j) {
            const int gc = bc + wc + 16 * j + m16;
            const float b = bias[gc];
#pragma unroll
            for (int r = 0; r < 4; ++r)
                C[(size_t)(gr + r) * N + gc] = acc[i][j][r] + b;
        }
    }
}

// ---------------------------------------------------------------------------
// Skinny GEMM: t[M,15] = h[M,K] @ wb[K,15] + bb. One wave per row.
// ---------------------------------------------------------------------------
__global__ void small_gemm(const float* __restrict__ h, const float* __restrict__ wb,
                           const float* __restrict__ bb, float* __restrict__ t, int K) {
    const int w = threadIdx.x >> 6, lane = threadIdx.x & 63;
    const int row = blockIdx.x * 4 + w;
    float acc[15] = {};
    for (int k = lane; k < K; k += 64) {
        const float a = h[(size_t)row * K + k];
        const float* wr = wb + k * 15;
#pragma unroll
        for (int c = 0; c < 15; ++c) acc[c] += a * wr[c];
    }
#pragma unroll
    for (int c = 0; c < 15; ++c)
#pragma unroll
        for (int off = 32; off > 0; off >>= 1) acc[c] += __shfl_xor(acc[c], off, 64);
    if (lane < 15) t[row * 15 + lane] = acc[lane] + bb[lane];
}

// ---------------------------------------------------------------------------
// Batch diversity: t (N,15) -> dv (N,5); dv[i,k] = sum_j exp(-L1(ti_k - tj_k))
// ---------------------------------------------------------------------------
__global__ void diversity_kernel(const float* __restrict__ t, float* __restrict__ dv, int N) {
    const int i = blockIdx.x;
    const int tid = threadIdx.x;
    float ti[15];
#pragma unroll
    for (int d = 0; d < 15; ++d) ti[d] = t[i * 15 + d];
    float acc[5] = {};
    for (int j = tid; j < N; j += 256) {
        const float* tj = t + j * 15;
#pragma unroll
        for (int k = 0; k < 5; ++k) {
            const float s = fabsf(ti[3 * k] - tj[3 * k])
                          + fabsf(ti[3 * k + 1] - tj[3 * k + 1])
                          + fabsf(ti[3 * k + 2] - tj[3 * k + 2]);
            acc[k] += __expf(-s);
        }
    }
    __shared__ float red[5][4];
    const int lane = tid & 63, wave = tid >> 6;
#pragma unroll
    for (int k = 0; k < 5; ++k) {
        float v = acc[k];
#pragma unroll
        for (int off = 32; off > 0; off >>= 1) v += __shfl_down(v, off, 64);
        if (lane == 0) red[k][wave] = v;
    }
    __syncthreads();
    if (tid < 5)
        dv[i * 5 + tid] = red[tid][0] + red[tid][1] + red[tid][2] + red[tid][3];
}

// ---------------------------------------------------------------------------
// concat([h, dv]) -> LayerNorm(center only) -> LeakyReLU.
// Writes fp32 out (M x 1029) and bf16 out (M x Cp), zero-padded cols [C,Cp).
// ---------------------------------------------------------------------------
__global__ void ln_lrelu(const float* __restrict__ h, const float* __restrict__ dvf,
                         const float* __restrict__ beta, float* __restrict__ out,
                         unsigned short* __restrict__ out_bf,
                         int H, int D, int Cp) {
    const int i = blockIdx.x;
    const int tid = threadIdx.x;
    const int C = H + D;
    float v[5];
    float s = 0.f, s2 = 0.f;
#pragma unroll
    for (int r = 0; r < 5; ++r) {
        const int c = tid + r * 256;
        if (c < C) {
            const float x = (c < H) ? h[(size_t)i * H + c] : dvf[i * D + (c - H)];
            v[r] = x; s += x; s2 += x * x;
        }
    }
    __shared__ float rs[4], rs2[4];
    const int lane = tid & 63, wave = tid >> 6;
#pragma unroll
    for (int off = 32; off > 0; off >>= 1) {
        s += __shfl_down(s, off, 64);
        s2 += __shfl_down(s2, off, 64);
    }
    if (lane == 0) { rs[wave] = s; rs2[wave] = s2; }
    __syncthreads();
    const float S = rs[0] + rs[1] + rs[2] + rs[3];
    const float S2 = rs2[0] + rs2[1] + rs2[2] + rs2[3];
    const float mu = S / (float)C;
    const float var = S2 / (float)C - mu * mu;
    const float rstd = rsqrtf(var + LN_EPS);
#pragma unroll
    for (int r = 0; r < 5; ++r) {
        const int c = tid + r * 256;
        if (c < C) {
            float y = (v[r] - mu) * rstd + beta[c];
            y = (y >= 0.f) ? y : LRELU_ALPHA * y;
            out[(size_t)i * C + c] = y;
            out_bf[(size_t)i * Cp + c] = f2bf(y);
        } else if (c < Cp) {
            out_bf[(size_t)i * Cp + c] = 0;  // zero K-pad for next MFMA GEMM
        }
    }
}

// ---------------------------------------------------------------------------
// Critic head: out[i] = hc[i,:] . wf + bf  (C = 1029)
// ---------------------------------------------------------------------------
__global__ void head_kernel(const float* __restrict__ hc, const float* __restrict__ wf,
                            const float* __restrict__ bf, float* __restrict__ out, int C) {
    const int i = blockIdx.x;
    const int tid = threadIdx.x;
    float s = 0.f;
    for (int c = tid; c < C; c += 256) s += hc[(size_t)i * C + c] * wf[c];
    __shared__ float rs[4];
    const int lane = tid & 63, wave = tid >> 6;
#pragma unroll
    for (int off = 32; off > 0; off >>= 1) s += __shfl_down(s, off, 64);
    if (lane == 0) rs[wave] = s;
    __syncthreads();
    if (tid == 0) out[i] = rs[0] + rs[1] + rs[2] + rs[3] + bf[0];
}

extern "C" void kernel_launch(void* const* d_in, const int* in_sizes, int n_in,
                              void* d_out, int out_size, void* d_ws, size_t ws_size,
                              hipStream_t stream) {
    const float* x     = (const float*)d_in[0];
    const float* w0a   = (const float*)d_in[1];
    const float* b0a   = (const float*)d_in[2];
    const float* w0b   = (const float*)d_in[3];
    const float* b0b   = (const float*)d_in[4];
    const float* beta0 = (const float*)d_in[5];
    const float* w1a   = (const float*)d_in[6];
    const float* b1a   = (const float*)d_in[7];
    const float* w1b   = (const float*)d_in[8];
    const float* b1b   = (const float*)d_in[9];
    const float* beta1 = (const float*)d_in[10];
    const float* wf    = (const float*)d_in[11];
    const float* bf    = (const float*)d_in[12];
    float* out = (float*)d_out;

    const int M = 4096, NF = 512, HID = 1024, C = 1029, CP = 1056;

    // fp32 workspace
    float* h  = (float*)d_ws;                       // 4096 x 1024
    float* hc = h  + (size_t)M * HID;               // 4096 x 1029
    float* t  = hc + (size_t)M * C;                 // 4096 x 15
    float* dv = t  + (size_t)M * 15;                // 4096 x 5
    // bf16 workspace
    unsigned short* x_bf  = (unsigned short*)(dv + (size_t)M * 5);   // 4096 x 512
    unsigned short* hc_bf = x_bf  + (size_t)M * NF;                  // 4096 x 1056
    unsigned short* w0aT  = hc_bf + (size_t)M * CP;                  // 1024 x 512
    unsigned short* w1aT  = w0aT  + (size_t)HID * NF;                // 1024 x 1056

    // casts (x and both big weights)
    cast_bf16<<<(M * NF) / 1024, 256, 0, stream>>>(x, x_bf, M * NF);
    transpose_cast<<<dim3(HID / 32, NF / 32), dim3(32, 8), 0, stream>>>(w0a, w0aT, NF, HID, NF);
    transpose_cast<<<dim3(HID / 32, CP / 32), dim3(32, 8), 0, stream>>>(w1a, w1aT, C, HID, CP);

    // ---- layer 0 ----
    mfma_gemm<<<dim3(HID / 64, M / 128), 256, 0, stream>>>(x_bf, NF, w0aT, NF, b0a, h, M, HID, NF);
    small_gemm<<<M / 4, 256, 0, stream>>>(h, w0b, b0b, t, HID);
    diversity_kernel<<<M, 256, 0, stream>>>(t, dv, M);
    ln_lrelu<<<M, 256, 0, stream>>>(h, dv, beta0, hc, hc_bf, HID, 5, CP);

    // ---- layer 1 ----
    mfma_gemm<<<dim3(HID / 64, M / 128), 256, 0, stream>>>(hc_bf, CP, w1aT, CP, b1a, h, M, HID, CP);
    small_gemm<<<M / 4, 256, 0, stream>>>(h, w1b, b1b, t, HID);
    diversity_kernel<<<M, 256, 0, stream>>>(t, dv, M);
    ln_lrelu<<<M, 256, 0, stream>>>(h, dv, beta1, hc, hc_bf, HID, 5, CP);

    // ---- head ----
    head_kernel<<<M, 256, 0, stream>>>(hc, wf, bf, out, C);
}